// Round 1
// baseline (1291.062 us; speedup 1.0000x reference)
//
#include <hip/hip_runtime.h>
#include <math.h>

#define B 64
#define T 128
#define D 256
#define H 256
#define G3 768   // 3*H

// ---------------------------------------------------------------------------
// Kernel 1: MX[b,t,:] = inputs[b,t,:] @ kernel + bias[0]
// rows = B*T = 8192, each block handles 16 rows, 256 threads = 1 col each x3 gates
// ---------------------------------------------------------------------------
__global__ __launch_bounds__(256) void mx_gemm_kernel(const float* __restrict__ x,
                                                      const float* __restrict__ K,
                                                      const float* __restrict__ bias,
                                                      float* __restrict__ MX) {
    __shared__ float xt[16][D];
    const int r0 = blockIdx.x * 16;
    const int tid = threadIdx.x;

    for (int idx = tid; idx < 16 * D; idx += 256) {
        xt[idx >> 8][idx & 255] = x[(size_t)(r0 + (idx >> 8)) * D + (idx & 255)];
    }
    __syncthreads();

    float acc0[16], acc1[16], acc2[16];
#pragma unroll
    for (int r = 0; r < 16; ++r) { acc0[r] = 0.f; acc1[r] = 0.f; acc2[r] = 0.f; }

    for (int d = 0; d < D; ++d) {
        float k0 = K[(size_t)d * G3 + tid];
        float k1 = K[(size_t)d * G3 + 256 + tid];
        float k2 = K[(size_t)d * G3 + 512 + tid];
#pragma unroll
        for (int r = 0; r < 16; ++r) {
            float xv = xt[r][d];
            acc0[r] += xv * k0;
            acc1[r] += xv * k1;
            acc2[r] += xv * k2;
        }
    }

    float b0 = bias[tid], b1 = bias[256 + tid], b2 = bias[512 + tid];
    for (int r = 0; r < 16; ++r) {
        size_t row = (size_t)(r0 + r) * G3;
        MX[row + tid]       = acc0[r] + b0;
        MX[row + 256 + tid] = acc1[r] + b1;
        MX[row + 512 + tid] = acc2[r] + b2;
    }
}

// ---------------------------------------------------------------------------
// Kernel 2: per-batch sequential GRU recurrence. One block per batch element.
// History lives in d_out (out[b,i,:] == h_i[b]); column tid is private to
// thread tid, so no sync is needed on history reads.
// ---------------------------------------------------------------------------
__global__ __launch_bounds__(256) void rnn_kernel(const float* __restrict__ cond,
                                                  const float* __restrict__ MX,
                                                  const float* __restrict__ R,
                                                  const float* __restrict__ bias,
                                                  float* __restrict__ out) {
    const int b = blockIdx.x;
    const int tid = threadIdx.x;

    __shared__ float c_row[T];
    __shared__ float hprev[H];
    __shared__ float mh[G3];

    const float* condb = cond + (size_t)b * T * T;
    const float* mxb   = MX   + (size_t)b * T * G3;
    float*       outb  = out  + (size_t)b * T * H;

    for (int i = 0; i < T; ++i) {
        if (tid < T) c_row[tid] = condb[(size_t)i * T + tid];
        __syncthreads();

        // phase 1: h_prev[tid] = sum_{j<i} c[i,j] * h_j[tid]  (column-private)
        float a0 = 0.f, a1 = 0.f, a2 = 0.f, a3 = 0.f;
        int j = 0;
        for (; j + 3 < i; j += 4) {
            a0 += c_row[j]     * outb[(size_t)(j)     * H + tid];
            a1 += c_row[j + 1] * outb[(size_t)(j + 1) * H + tid];
            a2 += c_row[j + 2] * outb[(size_t)(j + 2) * H + tid];
            a3 += c_row[j + 3] * outb[(size_t)(j + 3) * H + tid];
        }
        for (; j < i; ++j) a0 += c_row[j] * outb[(size_t)j * H + tid];
        float hp = (a0 + a1) + (a2 + a3);
        hprev[tid] = hp;
        __syncthreads();

        // phase 2: mh[g] = bias[1][g] + h_prev @ R[:,g]; threads 0..191, 4 cols each
        if (tid < 192) {
            int g4 = tid * 4;
            float4 acc;
            acc.x = bias[G3 + g4];
            acc.y = bias[G3 + g4 + 1];
            acc.z = bias[G3 + g4 + 2];
            acc.w = bias[G3 + g4 + 3];
            for (int h = 0; h < H; ++h) {
                float hv = hprev[h];
                float4 rv = *reinterpret_cast<const float4*>(&R[(size_t)h * G3 + g4]);
                acc.x += hv * rv.x;
                acc.y += hv * rv.y;
                acc.z += hv * rv.z;
                acc.w += hv * rv.w;
            }
            *reinterpret_cast<float4*>(&mh[g4]) = acc;
        }
        __syncthreads();

        // gates: thread tid owns hidden unit tid
        size_t mrow = (size_t)i * G3;
        float xz = mxb[mrow + tid];
        float xr = mxb[mrow + 256 + tid];
        float xh = mxb[mrow + 512 + tid];
        float z  = 1.f / (1.f + expf(-(xz + mh[tid])));
        float r  = 1.f / (1.f + expf(-(xr + mh[256 + tid])));
        float cand = tanhf(xh + r * mh[512 + tid]);
        float hnew = z * hp + (1.f - z) * cand;
        outb[(size_t)i * H + tid] = hnew;
        // no trailing sync needed: next-iter writers (c_row, hprev, mh) are all
        // separated from this iter's readers by the two syncs above.
    }
}

extern "C" void kernel_launch(void* const* d_in, const int* in_sizes, int n_in,
                              void* d_out, int out_size, void* d_ws, size_t ws_size,
                              hipStream_t stream) {
    const float* inputs     = (const float*)d_in[0];  // [B,T,D]
    const float* conditions = (const float*)d_in[1];  // [B,T,T]
    const float* kern       = (const float*)d_in[2];  // [D,3H]
    const float* rker       = (const float*)d_in[3];  // [H,3H]
    const float* bias       = (const float*)d_in[4];  // [2,3H]
    float* out = (float*)d_out;                       // [B,T,H]
    float* MX  = (float*)d_ws;                        // [B*T, 3H] = 25.2 MB scratch

    mx_gemm_kernel<<<(B * T) / 16, 256, 0, stream>>>(inputs, kern, bias, MX);
    rnn_kernel<<<B, 256, 0, stream>>>(conditions, MX, rker, bias, out);
}

// Round 2
// 1043.378 us; speedup vs baseline: 1.2374x; 1.2374x over previous
//
#include <hip/hip_runtime.h>
#include <math.h>

#define B 64
#define T 128
#define D 256
#define H 256
#define G3 768   // 3*H

// ---------------------------------------------------------------------------
// Kernel 1: MX[b,t,:] = inputs[b,t,:] @ kernel + bias[0]
// ---------------------------------------------------------------------------
__global__ __launch_bounds__(256) void mx_gemm_kernel(const float* __restrict__ x,
                                                      const float* __restrict__ K,
                                                      const float* __restrict__ bias,
                                                      float* __restrict__ MX) {
    __shared__ float xt[16][D];
    const int r0 = blockIdx.x * 16;
    const int tid = threadIdx.x;

    for (int idx = tid; idx < 16 * D; idx += 256) {
        xt[idx >> 8][idx & 255] = x[(size_t)(r0 + (idx >> 8)) * D + (idx & 255)];
    }
    __syncthreads();

    float acc0[16], acc1[16], acc2[16];
#pragma unroll
    for (int r = 0; r < 16; ++r) { acc0[r] = 0.f; acc1[r] = 0.f; acc2[r] = 0.f; }

    for (int d = 0; d < D; ++d) {
        float k0 = K[(size_t)d * G3 + tid];
        float k1 = K[(size_t)d * G3 + 256 + tid];
        float k2 = K[(size_t)d * G3 + 512 + tid];
#pragma unroll
        for (int r = 0; r < 16; ++r) {
            float xv = xt[r][d];
            acc0[r] += xv * k0;
            acc1[r] += xv * k1;
            acc2[r] += xv * k2;
        }
    }

    float b0 = bias[tid], b1 = bias[256 + tid], b2 = bias[512 + tid];
    for (int r = 0; r < 16; ++r) {
        size_t row = (size_t)(r0 + r) * G3;
        MX[row + tid]       = acc0[r] + b0;
        MX[row + 256 + tid] = acc1[r] + b1;
        MX[row + 512 + tid] = acc2[r] + b2;
    }
}

// ---------------------------------------------------------------------------
// Kernel 2: per-batch sequential GRU recurrence. One block (1024 thr) per batch.
//  phase1: hprev[h] = sum_{j<i} c[i,j]*out[j][h]   -- 4-way split over j + LDS reduce
//  phase2: mh[g]    = bias2[g] + sum_h hprev[h]*R[h][g]
//          4-way split over h (hq = tid/192, 3 waves each, wave-uniform)
//          cols as float4 (cg = tid%192 -> cols 4cg..4cg+3), coalesced R loads
//  phase3: gates by threads 0..255 (unit = tid), history lives in d_out.
// ---------------------------------------------------------------------------
__global__ __launch_bounds__(1024) void rnn_kernel(const float* __restrict__ cond,
                                                   const float* __restrict__ MX,
                                                   const float* __restrict__ R,
                                                   const float* __restrict__ bias,
                                                   float* __restrict__ out) {
    const int b = blockIdx.x;
    const int tid = threadIdx.x;

    __shared__ float c_row[T];
    __shared__ float hprev[H];
    __shared__ float mh[G3];
    __shared__ float p1[4][H];
    __shared__ float p2[4][G3];
    __shared__ float bias2[G3];

    if (tid < G3) bias2[tid] = bias[G3 + tid];

    const float* condb = cond + (size_t)b * T * T;
    const float* mxb   = MX   + (size_t)b * T * G3;
    float*       outb  = out  + (size_t)b * T * H;
    const float4* R4   = reinterpret_cast<const float4*>(R);

    const int q  = tid >> 8;    // 0..3  (phase-1 j-quarter)
    const int h  = tid & 255;   // phase-1 column
    const int hq = tid / 192;   // 0..3 for tid<768 (wave-uniform: 192 = 3 waves)
    const int cg = tid % 192;   // float4 column group -> cols 4cg..4cg+3

    for (int i = 0; i < T; ++i) {
        if (tid < T) c_row[tid] = condb[(size_t)i * T + tid];
        __syncthreads();

        // ---- phase 1: split the j-sum 4 ways ----
        const int len = (i + 3) >> 2;
        const int j0 = q * len;
        const int j1 = min(i, j0 + len);
        float a0 = 0.f, a1 = 0.f, a2 = 0.f, a3 = 0.f;
        int j = j0;
        for (; j + 3 < j1; j += 4) {
            a0 += c_row[j]     * outb[(size_t)(j)     * H + h];
            a1 += c_row[j + 1] * outb[(size_t)(j + 1) * H + h];
            a2 += c_row[j + 2] * outb[(size_t)(j + 2) * H + h];
            a3 += c_row[j + 3] * outb[(size_t)(j + 3) * H + h];
        }
        for (; j < j1; ++j) a0 += c_row[j] * outb[(size_t)j * H + h];
        p1[q][h] = (a0 + a1) + (a2 + a3);
        __syncthreads();

        float hp = 0.f;
        if (tid < H) {
            hp = p1[0][h] + p1[1][h] + p1[2][h] + p1[3][h];
            hprev[h] = hp;
        }
        __syncthreads();

        // ---- phase 2: mh = hprev @ R, 4-way h-split, float4 cols ----
        if (tid < 768) {
            float4 acc = make_float4(0.f, 0.f, 0.f, 0.f);
            const int h0 = hq * 64;
#pragma unroll 4
            for (int hh = h0; hh < h0 + 64; hh += 4) {
                float4 hp4 = *reinterpret_cast<float4*>(&hprev[hh]);
                float4 r0 = R4[(size_t)(hh + 0) * 192 + cg];
                float4 r1 = R4[(size_t)(hh + 1) * 192 + cg];
                float4 r2 = R4[(size_t)(hh + 2) * 192 + cg];
                float4 r3 = R4[(size_t)(hh + 3) * 192 + cg];
                acc.x += hp4.x * r0.x + hp4.y * r1.x + hp4.z * r2.x + hp4.w * r3.x;
                acc.y += hp4.x * r0.y + hp4.y * r1.y + hp4.z * r2.y + hp4.w * r3.y;
                acc.z += hp4.x * r0.z + hp4.y * r1.z + hp4.z * r2.z + hp4.w * r3.z;
                acc.w += hp4.x * r0.w + hp4.y * r1.w + hp4.z * r2.w + hp4.w * r3.w;
            }
            *reinterpret_cast<float4*>(&p2[hq][cg * 4]) = acc;
        }
        __syncthreads();
        if (tid < 768) {
            mh[tid] = p2[0][tid] + p2[1][tid] + p2[2][tid] + p2[3][tid] + bias2[tid];
        }
        __syncthreads();

        // ---- phase 3: gates ----
        if (tid < H) {
            const size_t mrow = (size_t)i * G3;
            const float xz = mxb[mrow + tid];
            const float xr = mxb[mrow + 256 + tid];
            const float xh = mxb[mrow + 512 + tid];
            const float z  = 1.f / (1.f + expf(-(xz + mh[tid])));
            const float r  = 1.f / (1.f + expf(-(xr + mh[256 + tid])));
            const float cand = tanhf(xh + r * mh[512 + tid]);
            outb[(size_t)i * H + tid] = z * hp + (1.f - z) * cand;
        }
        // top-of-loop __syncthreads (with its vmcnt drain) separates this global
        // write from next iteration's cross-thread phase-1 reads.
    }
}

extern "C" void kernel_launch(void* const* d_in, const int* in_sizes, int n_in,
                              void* d_out, int out_size, void* d_ws, size_t ws_size,
                              hipStream_t stream) {
    const float* inputs     = (const float*)d_in[0];  // [B,T,D]
    const float* conditions = (const float*)d_in[1];  // [B,T,T]
    const float* kern       = (const float*)d_in[2];  // [D,3H]
    const float* rker       = (const float*)d_in[3];  // [H,3H]
    const float* bias       = (const float*)d_in[4];  // [2,3H]
    float* out = (float*)d_out;                       // [B,T,H]
    float* MX  = (float*)d_ws;                        // [B*T, 3H]

    mx_gemm_kernel<<<(B * T) / 16, 256, 0, stream>>>(inputs, kern, bias, MX);
    rnn_kernel<<<B, 1024, 0, stream>>>(conditions, MX, rker, bias, out);
}

// Round 3
// 1003.667 us; speedup vs baseline: 1.2863x; 1.0396x over previous
//
#include <hip/hip_runtime.h>
#include <math.h>

#define B 64
#define T 128
#define D 256
#define H 256
#define G3 768   // 3*H
#define HP 130   // padded hist row length (floats): +2 -> 2-way (free) bank aliasing

// ---------------------------------------------------------------------------
// Kernel 1: MX[b,t,:] = inputs[b,t,:] @ kernel + bias[0]
// ---------------------------------------------------------------------------
__global__ __launch_bounds__(256) void mx_gemm_kernel(const float* __restrict__ x,
                                                      const float* __restrict__ K,
                                                      const float* __restrict__ bias,
                                                      float* __restrict__ MX) {
    __shared__ float xt[16][D];
    const int r0 = blockIdx.x * 16;
    const int tid = threadIdx.x;

    for (int idx = tid; idx < 16 * D; idx += 256) {
        xt[idx >> 8][idx & 255] = x[(size_t)(r0 + (idx >> 8)) * D + (idx & 255)];
    }
    __syncthreads();

    float acc0[16], acc1[16], acc2[16];
#pragma unroll
    for (int r = 0; r < 16; ++r) { acc0[r] = 0.f; acc1[r] = 0.f; acc2[r] = 0.f; }

    for (int d = 0; d < D; ++d) {
        float k0 = K[(size_t)d * G3 + tid];
        float k1 = K[(size_t)d * G3 + 256 + tid];
        float k2 = K[(size_t)d * G3 + 512 + tid];
#pragma unroll
        for (int r = 0; r < 16; ++r) {
            float xv = xt[r][d];
            acc0[r] += xv * k0;
            acc1[r] += xv * k1;
            acc2[r] += xv * k2;
        }
    }

    float b0 = bias[tid], b1 = bias[256 + tid], b2 = bias[512 + tid];
    for (int r = 0; r < 16; ++r) {
        size_t row = (size_t)(r0 + r) * G3;
        MX[row + tid]       = acc0[r] + b0;
        MX[row + 256 + tid] = acc1[r] + b1;
        MX[row + 512 + tid] = acc2[r] + b2;
    }
}

// ---------------------------------------------------------------------------
// Kernel 2: per-batch GRU recurrence, one 1024-thread block per batch.
// History kept in LDS (hist[h][j], transposed, padded) -> no global round-trip
// on the recurrent path. Per step:
//   barA -> phase1 (c from global L1-broadcast x hist from LDS -> p1 partials)
//   barB -> hprev reduce -> barC
//   MX-row prefetch (regs, tid<256) + phase2 (R stream from L2, 4 x 64-row split)
//   barD -> mh reduce (+bias) -> barE -> phase3 gates -> hist write + out store
// ---------------------------------------------------------------------------
__global__ __launch_bounds__(1024) void rnn_kernel(const float* __restrict__ cond,
                                                   const float* __restrict__ MX,
                                                   const float* __restrict__ R,
                                                   const float* __restrict__ bias,
                                                   float* __restrict__ out) {
    const int b = blockIdx.x;
    const int tid = threadIdx.x;

    __shared__ float hist[H][HP];                 // 133120 B
    __shared__ float p1[4][H];                    //   4096 B
    __shared__ __align__(16) float hprev[H];      //   1024 B
    __shared__ float p2[4][G3];                   //  12288 B
    __shared__ float mh[G3];                      //   3072 B
    // total 153600 B (<160 KiB)

    const float* condb = cond + (size_t)b * T * T;
    const float* mxb   = MX   + (size_t)b * T * G3;
    float*       outb  = out  + (size_t)b * T * H;
    const float4* R4   = reinterpret_cast<const float4*>(R);

    const int q  = tid >> 8;    // phase-1 j-quarter (wave-uniform)
    const int h  = tid & 255;   // phase-1 / phase-3 column
    const int hq = tid / 192;   // phase-2 row-quarter (wave-uniform, tid<768)
    const int cg = tid % 192;   // phase-2 float4 col group

    for (int i = 0; i < T; ++i) {
        __syncthreads();  // barA: hist[.][i-1] visible; p2/mh free for reuse

        // ---- phase 1: p1[q][h] = sum_{j in quarter q, j<i} c[i,j]*hist[h][j]
        const float* cr = condb + (size_t)i * T;
        const int len = (i + 3) >> 2;
        const int j0 = q * len;
        const int j1 = min(i, j0 + len);
        float a0 = 0.f, a1 = 0.f, a2 = 0.f, a3 = 0.f;
        int j = j0;
        for (; j + 3 < j1; j += 4) {
            a0 += cr[j]     * hist[h][j];
            a1 += cr[j + 1] * hist[h][j + 1];
            a2 += cr[j + 2] * hist[h][j + 2];
            a3 += cr[j + 3] * hist[h][j + 3];
        }
        for (; j < j1; ++j) a0 += cr[j] * hist[h][j];
        p1[q][h] = (a0 + a1) + (a2 + a3);
        __syncthreads();  // barB

        float hp = 0.f;
        if (tid < H) {
            hp = p1[0][h] + p1[1][h] + p1[2][h] + p1[3][h];
            hprev[h] = hp;
        }
        __syncthreads();  // barC

        // ---- MX-row prefetch into regs (independent; hides L3/HBM latency
        //      under phase 2; consumed after barD)
        float xz = 0.f, xr = 0.f, xh = 0.f;
        if (tid < H) {
            const float* mrow = mxb + (size_t)i * G3;
            xz = mrow[tid];
            xr = mrow[256 + tid];
            xh = mrow[512 + tid];
        }

        // ---- phase 2: p2[hq][:] = hprev[64hq:64hq+64] @ R[64hq:64hq+64, :]
        if (tid < 768) {
            float4 acc = make_float4(0.f, 0.f, 0.f, 0.f);
            const float4* hp4v = reinterpret_cast<const float4*>(&hprev[hq * 64]);
            const float4* Rrow = R4 + (size_t)(hq * 64) * 192 + cg;
#pragma unroll 4
            for (int s = 0; s < 16; ++s) {
                float4 hv = hp4v[s];
                float4 r0 = Rrow[(size_t)(4 * s + 0) * 192];
                float4 r1 = Rrow[(size_t)(4 * s + 1) * 192];
                float4 r2 = Rrow[(size_t)(4 * s + 2) * 192];
                float4 r3 = Rrow[(size_t)(4 * s + 3) * 192];
                acc.x += hv.x * r0.x + hv.y * r1.x + hv.z * r2.x + hv.w * r3.x;
                acc.y += hv.x * r0.y + hv.y * r1.y + hv.z * r2.y + hv.w * r3.y;
                acc.z += hv.x * r0.z + hv.y * r1.z + hv.z * r2.z + hv.w * r3.z;
                acc.w += hv.x * r0.w + hv.y * r1.w + hv.z * r2.w + hv.w * r3.w;
            }
            *reinterpret_cast<float4*>(&p2[hq][cg * 4]) = acc;
        }
        __syncthreads();  // barD

        if (tid < G3) {
            mh[tid] = p2[0][tid] + p2[1][tid] + p2[2][tid] + p2[3][tid]
                    + bias[G3 + tid];
        }
        __syncthreads();  // barE

        // ---- phase 3: gates; write new h to LDS hist + global out
        if (tid < H) {
            const float z    = 1.f / (1.f + expf(-(xz + mh[tid])));
            const float r    = 1.f / (1.f + expf(-(xr + mh[256 + tid])));
            const float cand = tanhf(xh + r * mh[512 + tid]);
            const float hnew = z * hp + (1.f - z) * cand;
            hist[tid][i] = hnew;
            outb[(size_t)i * H + tid] = hnew;
        }
    }
}

extern "C" void kernel_launch(void* const* d_in, const int* in_sizes, int n_in,
                              void* d_out, int out_size, void* d_ws, size_t ws_size,
                              hipStream_t stream) {
    const float* inputs     = (const float*)d_in[0];  // [B,T,D]
    const float* conditions = (const float*)d_in[1];  // [B,T,T]
    const float* kern       = (const float*)d_in[2];  // [D,3H]
    const float* rker       = (const float*)d_in[3];  // [H,3H]
    const float* bias       = (const float*)d_in[4];  // [2,3H]
    float* out = (float*)d_out;                       // [B,T,H]
    float* MX  = (float*)d_ws;                        // [B*T, 3H]

    mx_gemm_kernel<<<(B * T) / 16, 256, 0, stream>>>(inputs, kern, bias, MX);
    rnn_kernel<<<B, 1024, 0, stream>>>(conditions, MX, rker, bias, out);
}